// Round 5
// baseline (317.555 us; speedup 1.0000x reference)
//
#include <hip/hip_runtime.h>
#include <hip/hip_bf16.h>

#define S_LEN 2048
#define NHEAD 16
#define HDIM 64
#define EMB 1024

typedef short v8s __attribute__((ext_vector_type(8)));
typedef float v4f __attribute__((ext_vector_type(4)));

__device__ __forceinline__ float bflo(unsigned u) {
    union { unsigned u; float f; } v; v.u = u << 16; return v.f;
}
__device__ __forceinline__ float bfhi(unsigned u) {
    union { unsigned u; float f; } v; v.u = u & 0xFFFF0000u; return v.f;
}
// packed f32x2 -> bf16x2 (v_cvt_pk_bf16_f32 on gfx950), RNE
__device__ __forceinline__ unsigned cvtpk(float lo, float hi) {
    union { __hip_bfloat162 h2; unsigned u; } v;
    float2 f; f.x = lo; f.y = hi;
    v.h2 = __float22bfloat162_rn(f);
    return v.u;
}
__device__ __forceinline__ unsigned short f2bf(float f) {
    return (unsigned short)cvtpk(f, f);
}
__device__ __forceinline__ v8s cvt8(float4 a, float4 b) {
    v8s r;
    ((unsigned*)&r)[0] = cvtpk(a.x, a.y);
    ((unsigned*)&r)[1] = cvtpk(a.z, a.w);
    ((unsigned*)&r)[2] = cvtpk(b.x, b.y);
    ((unsigned*)&r)[3] = cvtpk(b.z, b.w);
    return r;
}

// ---------------------------------------------------------------------------
// K1: MFMA projections (R0-proven version) + W_fc convert plane.
// Grid (128 s-tiles of 32, 4 planes, 4 head-quarters), block = 2 waves.
// Planes y=0..2: q/k/v projections; wave = 16 s-rows x 4 heads.
//   Q/K: D = x @ W^T -> Qp/Kp [b][h][s][d], staged through wave-private LDS
//   so the global write is coalesced dwordx4.
//   V: D = W @ x^T -> Vt [b][h][d][s].
// Plane y=3: W_fc fp32 -> bf16 (was kernel k_cvtw; folded to save a launch).
//   512 blocks x 128 threads x 16 floats = exactly EMB*EMB.
// ---------------------------------------------------------------------------
__global__ __launch_bounds__(128) void k_proj2(
    const float* __restrict__ q, const float* __restrict__ k, const float* __restrict__ v,
    const float* __restrict__ Wq, const float* __restrict__ Wk, const float* __restrict__ Wv,
    const float* __restrict__ Wfc,
    unsigned short* __restrict__ Qp, unsigned short* __restrict__ Kp,
    unsigned short* __restrict__ Vt, unsigned short* __restrict__ Wb)
{
    __shared__ unsigned short Tq[2][16][72];       // wave-private bounce tiles
    const int t = threadIdx.x, wave = t >> 6, lane = t & 63;
    const int mtx = blockIdx.y;                    // 0:q 1:k 2:v 3:Wfc-convert

    if (mtx == 3) {
        const int bi = blockIdx.x * 4 + blockIdx.z;     // 0..511
        const int i = (bi * 128 + t) * 16;              // 16 floats/thread
        #pragma unroll
        for (int j = 0; j < 16; j += 4) {
            float4 wv = *(const float4*)(Wfc + i + j);
            uint2 pk;
            pk.x = cvtpk(wv.x, wv.y);
            pk.y = cvtpk(wv.z, wv.w);
            *(uint2*)(Wb + i + j) = pk;
        }
        return;
    }

    const int l15 = lane & 15, l4 = lane >> 4;
    const int hq = blockIdx.z;                     // head quarter
    const int row0 = blockIdx.x * 32 + wave * 16;  // global row in [0,4096)
    const int b = row0 >> 11, s0 = row0 & 2047;
    const float* X = (mtx == 0) ? q : (mtx == 1) ? k : v;
    const float* W = (mtx == 0) ? Wq : (mtx == 1) ? Wk : Wv;

    v8s wf[4][2];
    #pragma unroll
    for (int tile = 0; tile < 4; ++tile)
        #pragma unroll
        for (int c2 = 0; c2 < 2; ++c2) {
            const float* wp = W + (tile * 16 + l15) * 64 + c2 * 32 + l4 * 8;
            wf[tile][c2] = cvt8(*(const float4*)wp, *(const float4*)(wp + 4));
        }

    #pragma unroll
    for (int hi = 0; hi < 4; ++hi) {
        const int h = hq * 4 + hi;
        v8s xf[2];
        #pragma unroll
        for (int c2 = 0; c2 < 2; ++c2) {
            const float* xp = X + (size_t)(row0 + l15) * EMB + h * 64 + c2 * 32 + l4 * 8;
            xf[c2] = cvt8(*(const float4*)xp, *(const float4*)(xp + 4));
        }
        v4f acc[4];
        #pragma unroll
        for (int i = 0; i < 4; ++i) acc[i] = (v4f){0.f, 0.f, 0.f, 0.f};
        if (mtx < 2) {
            #pragma unroll
            for (int ns = 0; ns < 4; ++ns)
                #pragma unroll
                for (int c2 = 0; c2 < 2; ++c2)
                    acc[ns] = __builtin_amdgcn_mfma_f32_16x16x32_bf16(xf[c2], wf[ns][c2], acc[ns], 0, 0, 0);
            // stage C-frags (col=l15, rows l4*4+r) in LDS, wave-private
            #pragma unroll
            for (int ns = 0; ns < 4; ++ns)
                #pragma unroll
                for (int r = 0; r < 4; ++r)
                    Tq[wave][l4 * 4 + r][ns * 16 + l15] = f2bf(acc[ns][r]);
            // read back row-major, coalesced global store (lgkmcnt auto)
            const int row = lane >> 2, c8 = (lane & 3) * 16;
            uint4 d0 = *(const uint4*)&Tq[wave][row][c8];
            uint4 d1 = *(const uint4*)&Tq[wave][row][c8 + 8];
            unsigned short* dst = ((mtx == 0) ? Qp : Kp)
                + (size_t)(b * NHEAD + h) * S_LEN * HDIM + (size_t)(s0 + row) * HDIM + c8;
            *(uint4*)dst = d0;
            *(uint4*)(dst + 8) = d1;
        } else {
            #pragma unroll
            for (int ms = 0; ms < 4; ++ms)
                #pragma unroll
                for (int c2 = 0; c2 < 2; ++c2)
                    acc[ms] = __builtin_amdgcn_mfma_f32_16x16x32_bf16(wf[ms][c2], xf[c2], acc[ms], 0, 0, 0);
            unsigned short* dst = Vt + (size_t)(b * NHEAD + h) * HDIM * S_LEN;
            #pragma unroll
            for (int ms = 0; ms < 4; ++ms)
                #pragma unroll
                for (int r = 0; r < 4; ++r)
                    dst[(size_t)(ms * 16 + l4 * 4 + r) * S_LEN + s0 + l15] = f2bf(acc[ms][r]);
        }
    }
}

// ---------------------------------------------------------------------------
// K2: fused attention — EXACT R0 version (proven 113us). qT=64, k-quarter 512
// per block; block = 16 heads (wave w = head w) x 64 q rows; k-chunk 32.
// LDS: Pex[16][64][40] 80 KiB + Zr 5 KiB -> 1 block/CU, 16 waves.
// Session record: v2/v3 (software pipelining) and v4/v5 (swapped-QK,
// transpose-free P path) all regressed — block=1024 pins 4 waves/SIMD at the
// 128-reg cap (64 VGPR + 64 AGPR O-acc), so any live-range widening spills;
// and the LDS/VALU work removed by v5 was not the binding constraint
// (conflicts went UP at 20-dword stride). Do not restructure this kernel
// without per-phase ablation data.
// ---------------------------------------------------------------------------
__global__ __launch_bounds__(1024, 4) void k_fattn(
    const unsigned short* __restrict__ Qp, const unsigned short* __restrict__ Kp,
    const unsigned short* __restrict__ Vt, unsigned short* __restrict__ Op)
{
    __shared__ unsigned short Pex[16][64][40];   // 80 KiB (rows 80B: 16B-aligned)
    __shared__ unsigned ZrsU[64][20];            // 5 KiB, bf16x2 packed, 80B rows
    const int t = threadIdx.x, wave = t >> 6, lane = t & 63;
    const int l15 = lane & 15, l4 = lane >> 4;
    const int h = wave;
    const int id = blockIdx.x;
    const int slot = id & 7;
    const int kqb = slot & 3;         // k-quarter 0..3
    const int bsel = slot >> 2;       // batch
    const int qt = bsel * 32 + (id >> 3);   // q-tile of 64 rows, 0..63
    const int b = qt >> 5;
    const int q0 = (qt & 31) * 64;          // s-offset within batch
    const unsigned short* qh = Qp + (size_t)(b * NHEAD + h) * S_LEN * HDIM;
    const unsigned short* kh = Kp + (size_t)(b * NHEAD + h) * S_LEN * HDIM;
    const unsigned short* vh = Vt + (size_t)(b * NHEAD + h) * HDIM * S_LEN;

    v8s aq[4][2];
    #pragma unroll
    for (int qs = 0; qs < 4; ++qs)
        #pragma unroll
        for (int c2 = 0; c2 < 2; ++c2)
            aq[qs][c2] = *(const v8s*)(qh + (size_t)(q0 + qs * 16 + l15) * HDIM + c2 * 32 + l4 * 8);

    v4f o[4][4];
    #pragma unroll
    for (int qs = 0; qs < 4; ++qs)
        #pragma unroll
        for (int ds = 0; ds < 4; ++ds)
            o[qs][ds] = (v4f){0.f, 0.f, 0.f, 0.f};

    const int zq = t >> 4;          // 0..63: q row for Z-reduce
    const int zc = t & 15;          // col-pair index (2 cols each)

    for (int c = 0; c < 16; ++c) {
        const int kk0 = kqb * 512 + c * 32;
        // ---- phase 1: S = Q K^T (64q x 32k), exp -> Pex (wave-private plane)
        #pragma unroll
        for (int ks = 0; ks < 2; ++ks) {
            const unsigned short* kb = kh + (size_t)(kk0 + ks * 16 + l15) * HDIM + l4 * 8;
            v8s b0 = *(const v8s*)kb;
            v8s b1 = *(const v8s*)(kb + 32);
            #pragma unroll
            for (int qs = 0; qs < 4; ++qs) {
                v4f sf = (v4f){0.f, 0.f, 0.f, 0.f};
                sf = __builtin_amdgcn_mfma_f32_16x16x32_bf16(aq[qs][0], b0, sf, 0, 0, 0);
                sf = __builtin_amdgcn_mfma_f32_16x16x32_bf16(aq[qs][1], b1, sf, 0, 0, 0);
                const int rb = qs * 16 + l4 * 4;
                unsigned p01 = cvtpk(__expf(sf[0] * 0.03125f), __expf(sf[1] * 0.03125f));
                unsigned p23 = cvtpk(__expf(sf[2] * 0.03125f), __expf(sf[3] * 0.03125f));
                Pex[h][rb + 0][ks * 16 + l15] = (unsigned short)p01;
                Pex[h][rb + 1][ks * 16 + l15] = (unsigned short)(p01 >> 16);
                Pex[h][rb + 2][ks * 16 + l15] = (unsigned short)p23;
                Pex[h][rb + 3][ks * 16 + l15] = (unsigned short)(p23 >> 16);
            }
        }
        __syncthreads();
        // ---- phase 2 (all 1024 threads): Zr = 1/sum_h exp, packed bf16 ----
        {
            float z0 = 0.f, z1 = 0.f;
            #pragma unroll
            for (int hh = 0; hh < 16; ++hh) {
                unsigned u = *(const unsigned*)&Pex[hh][zq][zc * 2];
                z0 += bflo(u); z1 += bfhi(u);
            }
            ZrsU[zq][zc] = cvtpk(__builtin_amdgcn_rcpf(z0), __builtin_amdgcn_rcpf(z1));
        }
        __syncthreads();
        // ---- phase 3: normalize P (A-frag order) + PV MFMA (k=32) ----
        {
            v8s bv[4];
            #pragma unroll
            for (int ds = 0; ds < 4; ++ds)
                bv[ds] = *(const v8s*)(vh + (size_t)(ds * 16 + l15) * S_LEN + kk0 + l4 * 8);
            #pragma unroll
            for (int qs = 0; qs < 4; ++qs) {
                uint4 pu = *(const uint4*)&Pex[h][qs * 16 + l15][l4 * 8];
                uint4 zv = *(const uint4*)&ZrsU[qs * 16 + l15][l4 * 4];
                v8s pn;
                ((unsigned*)&pn)[0] = cvtpk(bflo(pu.x) * bflo(zv.x), bfhi(pu.x) * bfhi(zv.x));
                ((unsigned*)&pn)[1] = cvtpk(bflo(pu.y) * bflo(zv.y), bfhi(pu.y) * bfhi(zv.y));
                ((unsigned*)&pn)[2] = cvtpk(bflo(pu.z) * bflo(zv.z), bfhi(pu.z) * bfhi(zv.z));
                ((unsigned*)&pn)[3] = cvtpk(bflo(pu.w) * bflo(zv.w), bfhi(pu.w) * bfhi(zv.w));
                #pragma unroll
                for (int ds = 0; ds < 4; ++ds)
                    o[qs][ds] = __builtin_amdgcn_mfma_f32_16x16x32_bf16(pn, bv[ds], o[qs][ds], 0, 0, 0);
            }
        }
        // no 3rd barrier: Pex[h] is wave-private; ZrsU rewrite ordered by the
        // next iteration's two barriers.
    }

    // partial O plane for this (k-quarter, b), bf16
    unsigned short* op = Op + (size_t)(kqb * 2 + b) * S_LEN * EMB;
    #pragma unroll
    for (int qs = 0; qs < 4; ++qs)
        #pragma unroll
        for (int ds = 0; ds < 4; ++ds)
            #pragma unroll
            for (int r = 0; r < 4; ++r)
                op[(size_t)(q0 + qs * 16 + l4 * 4 + r) * EMB + h * 64 + ds * 16 + l15] =
                    f2bf(o[qs][ds][r]);
}

// ---------------------------------------------------------------------------
// K4: out = (sum_kq Op_kq) @ W_fc^T + b_fc   (M=4096, N=1024, K=1024), fp32.
// k_merge4 folded in: the A-fragment sums the 4 k-quarter partial planes on
// the fly (same f32 add order as the old merge kernel -> identical rounding).
// Saves the 40 MB merge pass + one launch. Linear dispatch puts all 16
// n-blocks of an m-slab on one XCD (lin%8 = x%8), so the 4-plane reads are
// L2-resident after first touch.
// Wave = 32 m-rows x 64 n-cols: 2 A-loads share each set of 4 B-loads.
// ---------------------------------------------------------------------------
__device__ __forceinline__ v8s ld_sum4(const unsigned short* __restrict__ p) {
    const size_t po = (size_t)2 * S_LEN * EMB;   // kq step = 2 planes
    uint4 u0 = *(const uint4*)(p);
    uint4 u1 = *(const uint4*)(p + po);
    uint4 u2 = *(const uint4*)(p + 2 * po);
    uint4 u3 = *(const uint4*)(p + 3 * po);
    v8s r;
    ((unsigned*)&r)[0] = cvtpk(bflo(u0.x) + bflo(u1.x) + bflo(u2.x) + bflo(u3.x),
                               bfhi(u0.x) + bfhi(u1.x) + bfhi(u2.x) + bfhi(u3.x));
    ((unsigned*)&r)[1] = cvtpk(bflo(u0.y) + bflo(u1.y) + bflo(u2.y) + bflo(u3.y),
                               bfhi(u0.y) + bfhi(u1.y) + bfhi(u2.y) + bfhi(u3.y));
    ((unsigned*)&r)[2] = cvtpk(bflo(u0.z) + bflo(u1.z) + bflo(u2.z) + bflo(u3.z),
                               bfhi(u0.z) + bfhi(u1.z) + bfhi(u2.z) + bfhi(u3.z));
    ((unsigned*)&r)[3] = cvtpk(bflo(u0.w) + bflo(u1.w) + bflo(u2.w) + bflo(u3.w),
                               bfhi(u0.w) + bfhi(u1.w) + bfhi(u2.w) + bfhi(u3.w));
    return r;
}

__global__ __launch_bounds__(256) void k_fc(
    const unsigned short* __restrict__ Op, const unsigned short* __restrict__ Wb,
    const float* __restrict__ bias, float* __restrict__ out)
{
    const int t = threadIdx.x, wave = t >> 6, lane = t & 63;
    const int l15 = lane & 15, l4 = lane >> 4;
    const int m0 = blockIdx.x * 128 + wave * 32;
    const int n0 = blockIdx.y * 64;
    const int b = m0 >> 11;              // constant per block (128 | 2048)
    const int s0 = m0 & 2047;
    const unsigned short* pa = Op + (size_t)b * S_LEN * EMB;
    v4f c[2][4];
    #pragma unroll
    for (int i = 0; i < 2; ++i)
        #pragma unroll
        for (int j = 0; j < 4; ++j) c[i][j] = (v4f){0.f, 0.f, 0.f, 0.f};
    for (int k = 0; k < EMB; k += 32) {
        v8s a0 = ld_sum4(pa + (size_t)(s0 + l15) * EMB + k + l4 * 8);
        v8s a1 = ld_sum4(pa + (size_t)(s0 + 16 + l15) * EMB + k + l4 * 8);
        #pragma unroll
        for (int ns = 0; ns < 4; ++ns) {
            v8s bw = *(const v8s*)(Wb + (size_t)(n0 + ns * 16 + l15) * EMB + k + l4 * 8);
            c[0][ns] = __builtin_amdgcn_mfma_f32_16x16x32_bf16(a0, bw, c[0][ns], 0, 0, 0);
            c[1][ns] = __builtin_amdgcn_mfma_f32_16x16x32_bf16(a1, bw, c[1][ns], 0, 0, 0);
        }
    }
    #pragma unroll
    for (int ms = 0; ms < 2; ++ms)
        #pragma unroll
        for (int ns = 0; ns < 4; ++ns) {
            const float bv = bias[n0 + ns * 16 + l15];
            #pragma unroll
            for (int r = 0; r < 4; ++r)
                out[(size_t)(m0 + ms * 16 + l4 * 4 + r) * EMB + n0 + ns * 16 + l15] = c[ms][ns][r] + bv;
        }
}

extern "C" void kernel_launch(void* const* d_in, const int* in_sizes, int n_in,
                              void* d_out, int out_size, void* d_ws, size_t ws_size,
                              hipStream_t stream)
{
    (void)in_sizes; (void)n_in; (void)out_size; (void)ws_size;
    const float* q   = (const float*)d_in[0];
    const float* k   = (const float*)d_in[1];
    const float* v   = (const float*)d_in[2];
    const float* Wq  = (const float*)d_in[3];
    const float* Wk  = (const float*)d_in[4];
    const float* Wv  = (const float*)d_in[5];
    const float* Wfc = (const float*)d_in[6];
    const float* bfc = (const float*)d_in[7];

    char* w = (char*)d_ws;
    unsigned short* Qp = (unsigned short*)(w);                      //  8 MiB
    unsigned short* Kp = (unsigned short*)(w + (8u  << 20));        //  8 MiB
    unsigned short* Vt = (unsigned short*)(w + (16u << 20));        //  8 MiB
    unsigned short* Wb = (unsigned short*)(w + (24u << 20));        //  2 MiB
    unsigned short* Op = (unsigned short*)(w + (26u << 20));        // 32 MiB (8 planes)

    k_proj2 <<<dim3(128, 4, 4), dim3(128),  0, stream>>>(q, k, v, Wq, Wk, Wv, Wfc, Qp, Kp, Vt, Wb);
    k_fattn <<<dim3(256),       dim3(1024), 0, stream>>>(Qp, Kp, Vt, Op);
    k_fc    <<<dim3(32, 16),    dim3(256),  0, stream>>>(Op, Wb, bfc, (float*)d_out);
}

// Round 6
// 303.976 us; speedup vs baseline: 1.0447x; 1.0447x over previous
//
#include <hip/hip_runtime.h>
#include <hip/hip_bf16.h>

#define S_LEN 2048
#define NHEAD 16
#define HDIM 64
#define EMB 1024

typedef short v8s __attribute__((ext_vector_type(8)));
typedef float v4f __attribute__((ext_vector_type(4)));

__device__ __forceinline__ float bflo(unsigned u) {
    union { unsigned u; float f; } v; v.u = u << 16; return v.f;
}
__device__ __forceinline__ float bfhi(unsigned u) {
    union { unsigned u; float f; } v; v.u = u & 0xFFFF0000u; return v.f;
}
// packed f32x2 -> bf16x2 (v_cvt_pk_bf16_f32 on gfx950), RNE
__device__ __forceinline__ unsigned cvtpk(float lo, float hi) {
    union { __hip_bfloat162 h2; unsigned u; } v;
    float2 f; f.x = lo; f.y = hi;
    v.h2 = __float22bfloat162_rn(f);
    return v.u;
}
__device__ __forceinline__ unsigned short f2bf(float f) {
    return (unsigned short)cvtpk(f, f);
}
__device__ __forceinline__ v8s cvt8(float4 a, float4 b) {
    v8s r;
    ((unsigned*)&r)[0] = cvtpk(a.x, a.y);
    ((unsigned*)&r)[1] = cvtpk(a.z, a.w);
    ((unsigned*)&r)[2] = cvtpk(b.x, b.y);
    ((unsigned*)&r)[3] = cvtpk(b.z, b.w);
    return r;
}

// ---------------------------------------------------------------------------
// K1: MFMA projections (R0-proven math) + W_fc convert plane.
// Grid (128 s-tiles of 32, 4 planes, 4 head-quarters), block = 2 waves.
// Planes y=0..2: q/k/v projections; wave = 16 s-rows x 4 heads.
//   Q/K: D = x @ W^T -> Qp/Kp [b][h][s][d], staged through wave-private LDS
//   so the global write is coalesced dwordx4.
//   V: D = W @ x^T -> Vt [b][h][d][s].
// Plane y=3: W_fc fp32 -> bf16 (folded k_cvtw; saves a launch).
// R6 change: per-hi LDS bounce quarters (Tq[wave][hi]) — the single reused
// tile created a WAR hazard between head-iterations (lgkmcnt drain each
// iter); 4 private quarters let the unrolled iterations overlap.
// ---------------------------------------------------------------------------
__global__ __launch_bounds__(128) void k_proj2(
    const float* __restrict__ q, const float* __restrict__ k, const float* __restrict__ v,
    const float* __restrict__ Wq, const float* __restrict__ Wk, const float* __restrict__ Wv,
    const float* __restrict__ Wfc,
    unsigned short* __restrict__ Qp, unsigned short* __restrict__ Kp,
    unsigned short* __restrict__ Vt, unsigned short* __restrict__ Wb)
{
    __shared__ unsigned short Tq[2][4][16][72];    // wave x head-iter bounce tiles
    const int t = threadIdx.x, wave = t >> 6, lane = t & 63;
    const int mtx = blockIdx.y;                    // 0:q 1:k 2:v 3:Wfc-convert

    if (mtx == 3) {
        const int bi = blockIdx.x * 4 + blockIdx.z;     // 0..511
        const int i = (bi * 128 + t) * 16;              // 16 floats/thread
        #pragma unroll
        for (int j = 0; j < 16; j += 4) {
            float4 wv = *(const float4*)(Wfc + i + j);
            uint2 pk;
            pk.x = cvtpk(wv.x, wv.y);
            pk.y = cvtpk(wv.z, wv.w);
            *(uint2*)(Wb + i + j) = pk;
        }
        return;
    }

    const int l15 = lane & 15, l4 = lane >> 4;
    const int hq = blockIdx.z;                     // head quarter
    const int row0 = blockIdx.x * 32 + wave * 16;  // global row in [0,4096)
    const int b = row0 >> 11, s0 = row0 & 2047;
    const float* X = (mtx == 0) ? q : (mtx == 1) ? k : v;
    const float* W = (mtx == 0) ? Wq : (mtx == 1) ? Wk : Wv;

    v8s wf[4][2];
    #pragma unroll
    for (int tile = 0; tile < 4; ++tile)
        #pragma unroll
        for (int c2 = 0; c2 < 2; ++c2) {
            const float* wp = W + (tile * 16 + l15) * 64 + c2 * 32 + l4 * 8;
            wf[tile][c2] = cvt8(*(const float4*)wp, *(const float4*)(wp + 4));
        }

    #pragma unroll
    for (int hi = 0; hi < 4; ++hi) {
        const int h = hq * 4 + hi;
        v8s xf[2];
        #pragma unroll
        for (int c2 = 0; c2 < 2; ++c2) {
            const float* xp = X + (size_t)(row0 + l15) * EMB + h * 64 + c2 * 32 + l4 * 8;
            xf[c2] = cvt8(*(const float4*)xp, *(const float4*)(xp + 4));
        }
        v4f acc[4];
        #pragma unroll
        for (int i = 0; i < 4; ++i) acc[i] = (v4f){0.f, 0.f, 0.f, 0.f};
        if (mtx < 2) {
            #pragma unroll
            for (int ns = 0; ns < 4; ++ns)
                #pragma unroll
                for (int c2 = 0; c2 < 2; ++c2)
                    acc[ns] = __builtin_amdgcn_mfma_f32_16x16x32_bf16(xf[c2], wf[ns][c2], acc[ns], 0, 0, 0);
            // stage C-frags (col=l15, rows l4*4+r) in LDS, wave/hi-private
            #pragma unroll
            for (int ns = 0; ns < 4; ++ns)
                #pragma unroll
                for (int r = 0; r < 4; ++r)
                    Tq[wave][hi][l4 * 4 + r][ns * 16 + l15] = f2bf(acc[ns][r]);
            // read back row-major, coalesced global store (lgkmcnt auto)
            const int row = lane >> 2, c8 = (lane & 3) * 16;
            uint4 d0 = *(const uint4*)&Tq[wave][hi][row][c8];
            uint4 d1 = *(const uint4*)&Tq[wave][hi][row][c8 + 8];
            unsigned short* dst = ((mtx == 0) ? Qp : Kp)
                + (size_t)(b * NHEAD + h) * S_LEN * HDIM + (size_t)(s0 + row) * HDIM + c8;
            *(uint4*)dst = d0;
            *(uint4*)(dst + 8) = d1;
        } else {
            #pragma unroll
            for (int ms = 0; ms < 4; ++ms)
                #pragma unroll
                for (int c2 = 0; c2 < 2; ++c2)
                    acc[ms] = __builtin_amdgcn_mfma_f32_16x16x32_bf16(wf[ms][c2], xf[c2], acc[ms], 0, 0, 0);
            unsigned short* dst = Vt + (size_t)(b * NHEAD + h) * HDIM * S_LEN;
            #pragma unroll
            for (int ms = 0; ms < 4; ++ms)
                #pragma unroll
                for (int r = 0; r < 4; ++r)
                    dst[(size_t)(ms * 16 + l4 * 4 + r) * S_LEN + s0 + l15] = f2bf(acc[ms][r]);
        }
    }
}

// ---------------------------------------------------------------------------
// K2: fused attention — EXACT R0 version (proven 113us). qT=64, k-quarter 512
// per block; block = 16 heads (wave w = head w) x 64 q rows; k-chunk 32.
// LDS: Pex[16][64][40] 80 KiB + Zr 5 KiB -> 1 block/CU, 16 waves.
// Session record: v2/v3 (software pipelining) and v4/v5 (swapped-QK,
// transpose-free P path) all regressed — block=1024 pins 4 waves/SIMD at the
// 128-reg cap (64 VGPR + 64 AGPR O-acc), so any live-range widening spills;
// and the LDS/VALU work removed by v5 was not the binding constraint.
// Do not restructure without per-phase ablation data.
// ---------------------------------------------------------------------------
__global__ __launch_bounds__(1024, 4) void k_fattn(
    const unsigned short* __restrict__ Qp, const unsigned short* __restrict__ Kp,
    const unsigned short* __restrict__ Vt, unsigned short* __restrict__ Op)
{
    __shared__ unsigned short Pex[16][64][40];   // 80 KiB (rows 80B: 16B-aligned)
    __shared__ unsigned ZrsU[64][20];            // 5 KiB, bf16x2 packed, 80B rows
    const int t = threadIdx.x, wave = t >> 6, lane = t & 63;
    const int l15 = lane & 15, l4 = lane >> 4;
    const int h = wave;
    const int id = blockIdx.x;
    const int slot = id & 7;
    const int kqb = slot & 3;         // k-quarter 0..3
    const int bsel = slot >> 2;       // batch
    const int qt = bsel * 32 + (id >> 3);   // q-tile of 64 rows, 0..63
    const int b = qt >> 5;
    const int q0 = (qt & 31) * 64;          // s-offset within batch
    const unsigned short* qh = Qp + (size_t)(b * NHEAD + h) * S_LEN * HDIM;
    const unsigned short* kh = Kp + (size_t)(b * NHEAD + h) * S_LEN * HDIM;
    const unsigned short* vh = Vt + (size_t)(b * NHEAD + h) * HDIM * S_LEN;

    v8s aq[4][2];
    #pragma unroll
    for (int qs = 0; qs < 4; ++qs)
        #pragma unroll
        for (int c2 = 0; c2 < 2; ++c2)
            aq[qs][c2] = *(const v8s*)(qh + (size_t)(q0 + qs * 16 + l15) * HDIM + c2 * 32 + l4 * 8);

    v4f o[4][4];
    #pragma unroll
    for (int qs = 0; qs < 4; ++qs)
        #pragma unroll
        for (int ds = 0; ds < 4; ++ds)
            o[qs][ds] = (v4f){0.f, 0.f, 0.f, 0.f};

    const int zq = t >> 4;          // 0..63: q row for Z-reduce
    const int zc = t & 15;          // col-pair index (2 cols each)

    for (int c = 0; c < 16; ++c) {
        const int kk0 = kqb * 512 + c * 32;
        // ---- phase 1: S = Q K^T (64q x 32k), exp -> Pex (wave-private plane)
        #pragma unroll
        for (int ks = 0; ks < 2; ++ks) {
            const unsigned short* kb = kh + (size_t)(kk0 + ks * 16 + l15) * HDIM + l4 * 8;
            v8s b0 = *(const v8s*)kb;
            v8s b1 = *(const v8s*)(kb + 32);
            #pragma unroll
            for (int qs = 0; qs < 4; ++qs) {
                v4f sf = (v4f){0.f, 0.f, 0.f, 0.f};
                sf = __builtin_amdgcn_mfma_f32_16x16x32_bf16(aq[qs][0], b0, sf, 0, 0, 0);
                sf = __builtin_amdgcn_mfma_f32_16x16x32_bf16(aq[qs][1], b1, sf, 0, 0, 0);
                const int rb = qs * 16 + l4 * 4;
                unsigned p01 = cvtpk(__expf(sf[0] * 0.03125f), __expf(sf[1] * 0.03125f));
                unsigned p23 = cvtpk(__expf(sf[2] * 0.03125f), __expf(sf[3] * 0.03125f));
                Pex[h][rb + 0][ks * 16 + l15] = (unsigned short)p01;
                Pex[h][rb + 1][ks * 16 + l15] = (unsigned short)(p01 >> 16);
                Pex[h][rb + 2][ks * 16 + l15] = (unsigned short)p23;
                Pex[h][rb + 3][ks * 16 + l15] = (unsigned short)(p23 >> 16);
            }
        }
        __syncthreads();
        // ---- phase 2 (all 1024 threads): Zr = 1/sum_h exp, packed bf16 ----
        {
            float z0 = 0.f, z1 = 0.f;
            #pragma unroll
            for (int hh = 0; hh < 16; ++hh) {
                unsigned u = *(const unsigned*)&Pex[hh][zq][zc * 2];
                z0 += bflo(u); z1 += bfhi(u);
            }
            ZrsU[zq][zc] = cvtpk(__builtin_amdgcn_rcpf(z0), __builtin_amdgcn_rcpf(z1));
        }
        __syncthreads();
        // ---- phase 3: normalize P (A-frag order) + PV MFMA (k=32) ----
        {
            v8s bv[4];
            #pragma unroll
            for (int ds = 0; ds < 4; ++ds)
                bv[ds] = *(const v8s*)(vh + (size_t)(ds * 16 + l15) * S_LEN + kk0 + l4 * 8);
            #pragma unroll
            for (int qs = 0; qs < 4; ++qs) {
                uint4 pu = *(const uint4*)&Pex[h][qs * 16 + l15][l4 * 8];
                uint4 zv = *(const uint4*)&ZrsU[qs * 16 + l15][l4 * 4];
                v8s pn;
                ((unsigned*)&pn)[0] = cvtpk(bflo(pu.x) * bflo(zv.x), bfhi(pu.x) * bfhi(zv.x));
                ((unsigned*)&pn)[1] = cvtpk(bflo(pu.y) * bflo(zv.y), bfhi(pu.y) * bfhi(zv.y));
                ((unsigned*)&pn)[2] = cvtpk(bflo(pu.z) * bflo(zv.z), bfhi(pu.z) * bfhi(zv.z));
                ((unsigned*)&pn)[3] = cvtpk(bflo(pu.w) * bflo(zv.w), bfhi(pu.w) * bfhi(zv.w));
                #pragma unroll
                for (int ds = 0; ds < 4; ++ds)
                    o[qs][ds] = __builtin_amdgcn_mfma_f32_16x16x32_bf16(pn, bv[ds], o[qs][ds], 0, 0, 0);
            }
        }
        // no 3rd barrier: Pex[h] is wave-private; ZrsU rewrite ordered by the
        // next iteration's two barriers.
    }

    // partial O plane for this (k-quarter, b), bf16
    unsigned short* op = Op + (size_t)(kqb * 2 + b) * S_LEN * EMB;
    #pragma unroll
    for (int qs = 0; qs < 4; ++qs)
        #pragma unroll
        for (int ds = 0; ds < 4; ++ds)
            #pragma unroll
            for (int r = 0; r < 4; ++r)
                op[(size_t)(q0 + qs * 16 + l4 * 4 + r) * EMB + h * 64 + ds * 16 + l15] =
                    f2bf(o[qs][ds][r]);
}

// ---------------------------------------------------------------------------
// K2b: merge the 4 k-quarter partials -> AO[b*2048+s][e] bf16 (R0-verbatim;
// the R5 attempt to fold this into k_fc recomputed the sum 16x across the
// n-broadcast and cost +40us — keep it as a separate streaming pass).
// ---------------------------------------------------------------------------
__global__ __launch_bounds__(256) void k_merge4(
    const unsigned short* __restrict__ Op, unsigned short* __restrict__ AO)
{
    const size_t i = ((size_t)blockIdx.x * 256 + threadIdx.x) * 8;
    const size_t row = i >> 10;                 // 0..4095
    const int b = (int)(row >> 11);
    const size_t off = (row & 2047) * EMB + (i & 1023);
    float a0 = 0, a1 = 0, a2 = 0, a3 = 0, a4 = 0, a5 = 0, a6 = 0, a7 = 0;
    #pragma unroll
    for (int kq = 0; kq < 4; ++kq) {
        uint4 u = *(const uint4*)(Op + (size_t)(kq * 2 + b) * S_LEN * EMB + off);
        a0 += bflo(u.x); a1 += bfhi(u.x);
        a2 += bflo(u.y); a3 += bfhi(u.y);
        a4 += bflo(u.z); a5 += bfhi(u.z);
        a6 += bflo(u.w); a7 += bfhi(u.w);
    }
    uint4 r;
    r.x = cvtpk(a0, a1); r.y = cvtpk(a2, a3);
    r.z = cvtpk(a4, a5); r.w = cvtpk(a6, a7);
    *(uint4*)(AO + i) = r;
}

// ---------------------------------------------------------------------------
// K4: out = AO @ W_fc^T + b_fc   (M=4096, N=1024, K=1024), fp32 out.
// R6: wave tile 32x64 -> 16x64, grid (64,16): 4096 waves = 4 waves/SIMD
// (was 2) for a latency-bound direct-from-L2 loop; #pragma unroll 2 lets
// iter k+1 loads issue under iter k MFMAs. Per-accumulator K-order is
// unchanged -> bitwise-identical output to R0.
// ---------------------------------------------------------------------------
__global__ __launch_bounds__(256) void k_fc(
    const unsigned short* __restrict__ AO, const unsigned short* __restrict__ Wb,
    const float* __restrict__ bias, float* __restrict__ out)
{
    const int t = threadIdx.x, wave = t >> 6, lane = t & 63;
    const int l15 = lane & 15, l4 = lane >> 4;
    const int m0 = blockIdx.x * 64 + wave * 16;
    const int n0 = blockIdx.y * 64;
    v4f c[4];
    #pragma unroll
    for (int j = 0; j < 4; ++j) c[j] = (v4f){0.f, 0.f, 0.f, 0.f};
    #pragma unroll 2
    for (int k = 0; k < EMB; k += 32) {
        v8s a0 = *(const v8s*)(AO + (size_t)(m0 + l15) * EMB + k + l4 * 8);
        #pragma unroll
        for (int ns = 0; ns < 4; ++ns) {
            v8s bw = *(const v8s*)(Wb + (size_t)(n0 + ns * 16 + l15) * EMB + k + l4 * 8);
            c[ns] = __builtin_amdgcn_mfma_f32_16x16x32_bf16(a0, bw, c[ns], 0, 0, 0);
        }
    }
    #pragma unroll
    for (int ns = 0; ns < 4; ++ns) {
        const float bv = bias[n0 + ns * 16 + l15];
        #pragma unroll
        for (int r = 0; r < 4; ++r)
            out[(size_t)(m0 + l4 * 4 + r) * EMB + n0 + ns * 16 + l15] = c[ns][r] + bv;
    }
}

extern "C" void kernel_launch(void* const* d_in, const int* in_sizes, int n_in,
                              void* d_out, int out_size, void* d_ws, size_t ws_size,
                              hipStream_t stream)
{
    (void)in_sizes; (void)n_in; (void)out_size; (void)ws_size;
    const float* q   = (const float*)d_in[0];
    const float* k   = (const float*)d_in[1];
    const float* v   = (const float*)d_in[2];
    const float* Wq  = (const float*)d_in[3];
    const float* Wk  = (const float*)d_in[4];
    const float* Wv  = (const float*)d_in[5];
    const float* Wfc = (const float*)d_in[6];
    const float* bfc = (const float*)d_in[7];

    char* w = (char*)d_ws;
    unsigned short* Qp = (unsigned short*)(w);                      //  8 MiB (AO overlays after k_fattn)
    unsigned short* Kp = (unsigned short*)(w + (8u  << 20));        //  8 MiB
    unsigned short* Vt = (unsigned short*)(w + (16u << 20));        //  8 MiB
    unsigned short* Wb = (unsigned short*)(w + (24u << 20));        //  2 MiB
    unsigned short* Op = (unsigned short*)(w + (26u << 20));        // 32 MiB (8 planes)
    unsigned short* AO = Qp;                                        // reuse (Qp dead post-attn)

    k_proj2 <<<dim3(128, 4, 4), dim3(128),  0, stream>>>(q, k, v, Wq, Wk, Wv, Wfc, Qp, Kp, Vt, Wb);
    k_fattn <<<dim3(256),       dim3(1024), 0, stream>>>(Qp, Kp, Vt, Op);
    k_merge4<<<dim3(2048),      dim3(256),  0, stream>>>(Op, AO);
    k_fc    <<<dim3(64, 16),    dim3(256),  0, stream>>>(AO, Wb, bfc, (float*)d_out);
}